// Round 1
// 786.224 us; speedup vs baseline: 1.1417x; 1.1417x over previous
//
#include <hip/hip_runtime.h>
#include <hip/hip_bf16.h>
#include <math.h>

// x:(B,P,D) W1:(P,D,D)[d_out,e] b1:(P,D) W2:(P,D,D) b2:(P,D) gamma,beta:(D)
// out:(B,P,D).  B=2048 P=54 D=512.
//
// Round 1 restructure:
//  - cvt_bf16: W1,W2 fp32 -> bf16 ONCE into ws (was: every block re-converted
//    its W tile every K-step = 64x redundant VALU + 2x fetch bytes).
//  - mlp_fused: one kernel per (64 rows x patch): GEMM1 -> GELU -> GEMM2 -> LN.
//    h never touches global (113 MB write + 113 MB read removed); h lives in
//    the same LDS buffer that held the x tile.
//  - Weight K-strips staged with global_load_lds width=16 (no reg round-trip,
//    no per-step cvt), 1-deep double-buffer prefetch: stage(t+1) issued right
//    after the barrier, drained by the NEXT iteration's __syncthreads (its
//    implicit vmcnt(0) is exactly the wait we need) -> load latency hides
//    under frag reads + MFMA.
//  - A-tile (x/h, 1024 B row stride) XOR-swizzled: addr ^ ((row&7)<<4);
//    unswizzled it is a 16-way bank conflict on ds_read_b128. W strip keeps
//    64 B rows = full-coverage conflict-free, so linear gload dest is fine.
//  - GEMM1 runs with SWAPPED mfma operands (mfma(W1frag, xfrag)) so each lane
//    holds 4 consecutive h-columns -> cvt_pk pairs -> ds_write_b64 row-major
//    packed h, which GEMM2 reads back as standard A fragments.

#define B_DIM 2048
#define P_DIM 54
#define D_DIM 512
#define WTILE (D_DIM * D_DIM)

typedef __attribute__((ext_vector_type(8))) short short8;
typedef __attribute__((ext_vector_type(4))) float floatx4;

__device__ __forceinline__ unsigned int f2bf2(float a, float b) {
    __hip_bfloat162 h2 = __float22bfloat162_rn(make_float2(a, b));
    unsigned int u; __builtin_memcpy(&u, &h2, 4); return u;
}

__device__ __forceinline__ void gload_lds16(const unsigned short* g, unsigned short* l) {
    __builtin_amdgcn_global_load_lds((const __attribute__((address_space(1))) void*)g,
                                     (__attribute__((address_space(3))) void*)l,
                                     16, 0, 0);
}

// ---------------------------------------------------------------------------
// fp32 -> bf16 pre-convert, 8 elems/thread, exact grid.
// ---------------------------------------------------------------------------
__global__ __launch_bounds__(256) void cvt_bf16(const float* __restrict__ src,
                                                unsigned short* __restrict__ dst,
                                                int n8) {
    const int i = blockIdx.x * 256 + threadIdx.x;
    if (i >= n8) return;
    const float4 v0 = ((const float4*)src)[2 * i];
    const float4 v1 = ((const float4*)src)[2 * i + 1];
    uint4 o;
    o.x = f2bf2(v0.x, v0.y); o.y = f2bf2(v0.z, v0.w);
    o.z = f2bf2(v1.x, v1.y); o.w = f2bf2(v1.z, v1.w);
    ((uint4*)dst)[i] = o;
}

// ---------------------------------------------------------------------------
// Fused MLP block: 64 rows x one patch per block. 512 threads = 8 waves,
// wave w owns output columns [w*64, w*64+64) in both GEMMs.
// LDS: sXH 64x512 bf16 (x tile, then h tile, XOR-swizzled) = 64 KB
//      sW  2 x [512 rows x 32 k] bf16 (linear, gload_lds dest)  = 64 KB
// ---------------------------------------------------------------------------
__global__ __launch_bounds__(512) void mlp_fused(
    const float* __restrict__ x,
    const unsigned short* __restrict__ W1b,
    const float* __restrict__ b1,
    const unsigned short* __restrict__ W2b,
    const float* __restrict__ b2,
    const float* __restrict__ gamma,
    const float* __restrict__ beta,
    float* __restrict__ out)
{
    __shared__ __align__(16) unsigned short sXH[64 * 512];
    __shared__ __align__(16) unsigned short sW[2][512 * 32];
    __shared__ float red1[64 * 8];
    __shared__ float red2[64 * 8];
    __shared__ float sMu[64], sRs[64];

    const int tid   = threadIdx.x;
    const int wave  = tid >> 6;
    const int lane  = tid & 63;
    const int quad  = lane >> 4;
    const int colid = lane & 15;
    const int wn    = wave * 64;

    const int m0 = blockIdx.x * 64;
    const int p  = blockIdx.y;

    const long rstride = (long)P_DIM * D_DIM;
    const float*          xp  = x   + (long)m0 * rstride + (long)p * D_DIM;
    const unsigned short* w1p = W1b + (long)p * WTILE;
    const unsigned short* w2p = W2b + (long)p * WTILE;

    // W-stage lane map: round r, thread t -> LDS byte d = r*8192 + t*16
    //   row = d>>6 = r*128 + (t>>2), k-subgroup = (t&3)*8 elements.
    const int wrow0 = tid >> 2;
    const int wk8   = (tid & 3) * 8;

    // ---- issue W1 k-tile 0 stage (async), then pack x tile (covers latency) --
#pragma unroll
    for (int r = 0; r < 4; r++)
        gload_lds16(w1p + (r * 128 + wrow0) * D_DIM + wk8,
                    &sW[0][r * 4096 + wave * 512]);

#pragma unroll
    for (int i = 0; i < 8; i++) {
        const int row = i * 8 + wave;                 // row & 7 == wave
        const float* xrow = xp + (long)row * rstride + lane * 8;
        const float4 v0 = *(const float4*)(xrow);
        const float4 v1 = *(const float4*)(xrow + 4);
        uint4 o;
        o.x = f2bf2(v0.x, v0.y); o.y = f2bf2(v0.z, v0.w);
        o.z = f2bf2(v1.x, v1.y); o.w = f2bf2(v1.z, v1.w);
        const int ba = (row * 1024 + lane * 16) ^ ((wave & 7) << 4);
        *(uint4*)((char*)sXH + ba) = o;
    }

    // Fragment offsets.
    // A (sXH): rows i*16+colid, byte = (row*1024 + kt*2 + quad*16) ^ ((row&7)<<4)
    //          note (row&7) == (colid&7) since 16 == 0 mod 8.
    // B (sW):  rows wn+i*16+colid, byte = row*64 + quad*16 (linear, conflict-free)
    const int axor = (colid & 7) << 4;
    int aoff[4], boff[4];
#pragma unroll
    for (int i = 0; i < 4; i++) {
        aoff[i] = (i * 16 + colid) * 1024 + quad * 16;
        boff[i] = (wn + i * 16 + colid) * 64 + quad * 16;
    }

    floatx4 acc[4][4];
#pragma unroll
    for (int i = 0; i < 4; i++)
#pragma unroll
        for (int j = 0; j < 4; j++)
            acc[i][j] = (floatx4){0.f, 0.f, 0.f, 0.f};

    int cur = 0;

    // ---- GEMM1: swapped operands -> acc[ni][mj] holds h^T fragments
    //      (lane: n = wn + ni*16 + quad*4 + r ; m = mj*16 + colid)
    for (int t = 0; t < 16; t++) {
        __syncthreads();   // drains stage into sW[cur]; syncs waves
        {
            // prefetch next strip: W1 tile t+1, or W2 tile 0 at the seam
            const unsigned short* nsrc = (t < 15) ? (w1p + (t + 1) * 32) : w2p;
            unsigned short* nbuf = &sW[cur ^ 1][0];
#pragma unroll
            for (int r = 0; r < 4; r++)
                gload_lds16(nsrc + (r * 128 + wrow0) * D_DIM + wk8,
                            nbuf + r * 4096 + wave * 512);
        }
        const int kt2 = t * 64;   // byte offset of k-strip within a row
        short8 xa[4], wb[4];
        const char* sWc = (const char*)&sW[cur][0];
#pragma unroll
        for (int i = 0; i < 4; i++) {
            xa[i] = *(const short8*)((const char*)sXH + ((aoff[i] + kt2) ^ axor));
            wb[i] = *(const short8*)(sWc + boff[i]);
        }
#pragma unroll
        for (int ni = 0; ni < 4; ni++)
#pragma unroll
            for (int mj = 0; mj < 4; mj++)
                acc[ni][mj] = __builtin_amdgcn_mfma_f32_16x16x32_bf16(
                    wb[ni], xa[mj], acc[ni][mj], 0, 0, 0);
        cur ^= 1;
    }

    __syncthreads();   // all waves done reading sXH(x); W2 tile 0 landed

    // ---- bias + exact-erf GELU, pack h -> sXH (bf16, swizzled) ----
#pragma unroll
    for (int ni = 0; ni < 4; ni++) {
        const int nbase = wn + ni * 16 + quad * 4;
        const float4 bv = *(const float4*)(b1 + p * D_DIM + nbase);
#pragma unroll
        for (int mj = 0; mj < 4; mj++) {
            const int m = mj * 16 + colid;
            float g0 = acc[ni][mj][0] + bv.x;
            float g1 = acc[ni][mj][1] + bv.y;
            float g2 = acc[ni][mj][2] + bv.z;
            float g3 = acc[ni][mj][3] + bv.w;
            g0 = 0.5f * g0 * (1.0f + erff(g0 * 0.70710678118654752f));
            g1 = 0.5f * g1 * (1.0f + erff(g1 * 0.70710678118654752f));
            g2 = 0.5f * g2 * (1.0f + erff(g2 * 0.70710678118654752f));
            g3 = 0.5f * g3 * (1.0f + erff(g3 * 0.70710678118654752f));
            uint2 o; o.x = f2bf2(g0, g1); o.y = f2bf2(g2, g3);
            const int ba = (m * 1024 + nbase * 2) ^ ((colid & 7) << 4);
            *(uint2*)((char*)sXH + ba) = o;
        }
    }

#pragma unroll
    for (int i = 0; i < 4; i++)
#pragma unroll
        for (int j = 0; j < 4; j++)
            acc[i][j] = (floatx4){0.f, 0.f, 0.f, 0.f};

    // ---- GEMM2: standard orientation (rows = m from h, cols = n2 from W2) ----
    for (int t = 0; t < 16; t++) {
        __syncthreads();   // makes sH visible (t=0) / drains stage into sW[cur]
        if (t < 15) {
            const unsigned short* nsrc = w2p + (t + 1) * 32;
            unsigned short* nbuf = &sW[cur ^ 1][0];
#pragma unroll
            for (int r = 0; r < 4; r++)
                gload_lds16(nsrc + (r * 128 + wrow0) * D_DIM + wk8,
                            nbuf + r * 4096 + wave * 512);
        }
        const int kt2 = t * 64;
        short8 ha[4], wb[4];
        const char* sWc = (const char*)&sW[cur][0];
#pragma unroll
        for (int i = 0; i < 4; i++) {
            ha[i] = *(const short8*)((const char*)sXH + ((aoff[i] + kt2) ^ axor));
            wb[i] = *(const short8*)(sWc + boff[i]);
        }
#pragma unroll
        for (int i = 0; i < 4; i++)
#pragma unroll
            for (int j = 0; j < 4; j++)
                acc[i][j] = __builtin_amdgcn_mfma_f32_16x16x32_bf16(
                    ha[i], wb[j], acc[i][j], 0, 0, 0);
        cur ^= 1;
    }

    // ---- epilogue: +b2 + residual (fp32 x), LayerNorm, store ----
#pragma unroll
    for (int j = 0; j < 4; j++) {
        const int n = wn + j * 16 + colid;
        const float bias = b2[p * D_DIM + n];
#pragma unroll
        for (int i = 0; i < 4; i++) {
#pragma unroll
            for (int r = 0; r < 4; r++) {
                const int row = i * 16 + quad * 4 + r;
                acc[i][j][r] += bias + xp[(long)row * rstride + n];
            }
        }
    }

#pragma unroll
    for (int i = 0; i < 4; i++) {
#pragma unroll
        for (int r = 0; r < 4; r++) {
            float s1 = 0.f, s2 = 0.f;
#pragma unroll
            for (int j = 0; j < 4; j++) {
                const float v = acc[i][j][r];
                s1 += v; s2 += v * v;
            }
#pragma unroll
            for (int off = 1; off < 16; off <<= 1) {
                s1 += __shfl_xor(s1, off, 16);
                s2 += __shfl_xor(s2, off, 16);
            }
            if (colid == 0) {
                const int row = i * 16 + quad * 4 + r;
                red1[row * 8 + wave] = s1;
                red2[row * 8 + wave] = s2;
            }
        }
    }
    __syncthreads();
    if (tid < 64) {
        float s1 = 0.f, s2 = 0.f;
#pragma unroll
        for (int w = 0; w < 8; w++) { s1 += red1[tid * 8 + w]; s2 += red2[tid * 8 + w]; }
        const float mu  = s1 * (1.0f / (float)D_DIM);
        const float var = s2 * (1.0f / (float)D_DIM) - mu * mu;
        sMu[tid] = mu;
        sRs[tid] = rsqrtf(var + 1e-5f);
    }
    __syncthreads();

    float* op = out + (long)m0 * rstride + (long)p * D_DIM;
#pragma unroll
    for (int j = 0; j < 4; j++) {
        const int n = wn + j * 16 + colid;
        const float g = gamma[n], bt = beta[n];
#pragma unroll
        for (int i = 0; i < 4; i++) {
#pragma unroll
            for (int r = 0; r < 4; r++) {
                const int row = i * 16 + quad * 4 + r;
                const float v = (acc[i][j][r] - sMu[row]) * sRs[row] * g + bt;
                op[(long)row * rstride + n] = v;
            }
        }
    }
}

extern "C" void kernel_launch(void* const* d_in, const int* in_sizes, int n_in,
                              void* d_out, int out_size, void* d_ws, size_t ws_size,
                              hipStream_t stream) {
    const float* x     = (const float*)d_in[0];
    const float* W1    = (const float*)d_in[1];
    const float* b1    = (const float*)d_in[2];
    const float* W2    = (const float*)d_in[3];
    const float* b2    = (const float*)d_in[4];
    const float* gamma = (const float*)d_in[5];
    const float* beta  = (const float*)d_in[6];
    float* out = (float*)d_out;

    unsigned short* W1b = (unsigned short*)d_ws;            // 28.3 MB
    unsigned short* W2b = W1b + (long)P_DIM * WTILE;        // 28.3 MB (ws >= 113 MB)

    const int n8 = (P_DIM * WTILE) / 8;                     // 1,769,472 = 6912*256
    cvt_bf16<<<n8 / 256, 256, 0, stream>>>(W1, W1b, n8);
    cvt_bf16<<<n8 / 256, 256, 0, stream>>>(W2, W2b, n8);

    dim3 grid(B_DIM / 64, P_DIM);
    mlp_fused<<<grid, 512, 0, stream>>>(x, W1b, b1, W2b, b2, gamma, beta, out);
}